// Round 3
// baseline (1723.011 us; speedup 1.0000x reference)
//
#include <hip/hip_runtime.h>
#include <hip/hip_bf16.h>

#define DIM 64
#define NCLS_OUT 40

typedef __hip_bfloat16 bf16;

__device__ __forceinline__ float lane_bcast(float v, int l) {
  return __int_as_float(__builtin_amdgcn_readlane(__float_as_int(v), l));
}

// mode: 1 = float inputs/outputs stored as f32, 0 = stored as bf16
__device__ __forceinline__ float ldf(const void* p, long i, int m) {
  return m ? ((const float*)p)[i] : __bfloat162float(((const bf16*)p)[i]);
}
__device__ __forceinline__ void stf(void* p, long i, float v, int m) {
  if (m) ((float*)p)[i] = v;
  else ((bf16*)p)[i] = __float2bfloat16(v);
}

// ---- dtype detector: are float arrays f32-stored or bf16-stored? ----
__global__ void k_detect(const unsigned int* __restrict__ wds, int nw, int* __restrict__ mode) {
  __shared__ int cnt_s;
  if (threadIdx.x == 0) cnt_s = 0;
  __syncthreads();
  int c = 0;
  for (int i = threadIdx.x; i < nw; i += 256) {
    unsigned h = wds[i] & 0xFFFFu;         // low 16 bits of each 32-bit word
    unsigned e = (h >> 7) & 0xFFu;         // exponent field if this were a bf16
    if (e == 0xFFu || (e != 0u && e < 0x60u)) c++;  // impossible for N(0,1) bf16 data
  }
  atomicAdd(&cnt_s, c);
  __syncthreads();
  if (threadIdx.x == 0) *mode = (cnt_s > nw / 16) ? 1 : 0;
}

// ---- degree count ----
__global__ void k_deg(const int* __restrict__ src, const int* __restrict__ dst,
                      int* __restrict__ dout, int* __restrict__ din, int e) {
  int i = blockIdx.x * 256 + threadIdx.x;
  if (i < e) {
    atomicAdd(&dout[src[i]], 1);
    atomicAdd(&din[dst[i]], 1);
  }
}

// ---- norms = rsqrt(max(deg,1)) ----
__global__ void k_norm(const int* __restrict__ deg, float* __restrict__ nrm, int n4) {
  int i = blockIdx.x * 256 + threadIdx.x;
  if (i < n4) {
    int d = deg[i];
    if (d < 1) d = 1;
    nrm[i] = rsqrtf((float)d);
  }
}

// ---- scan pass 1: per-block sums (1024 elems/block) ----
__global__ void k_scan1(const int* __restrict__ x, int* __restrict__ bsum, int n) {
  __shared__ int sm[256];
  int t = threadIdx.x;
  int base = blockIdx.x * 1024 + t * 4;
  int s = 0;
#pragma unroll
  for (int k = 0; k < 4; ++k) {
    int i = base + k;
    if (i < n) s += x[i];
  }
  sm[t] = s;
  __syncthreads();
  for (int o = 128; o > 0; o >>= 1) {
    if (t < o) sm[t] += sm[t + o];
    __syncthreads();
  }
  if (t == 0) bsum[blockIdx.x] = sm[0];
}

// ---- scan pass 2: exclusive scan of block sums (single block) ----
__global__ void k_scan2(int* __restrict__ bsum, int nb) {
  __shared__ int sm[256];
  __shared__ int carry_s;
  int t = threadIdx.x;
  if (t == 0) carry_s = 0;
  __syncthreads();
  for (int base = 0; base < nb; base += 256) {
    int i = base + t;
    int v = (i < nb) ? bsum[i] : 0;
    sm[t] = v;
    __syncthreads();
    for (int o = 1; o < 256; o <<= 1) {
      int a = (t >= o) ? sm[t - o] : 0;
      __syncthreads();
      sm[t] += a;
      __syncthreads();
    }
    int incl = sm[t];
    int tot = sm[255];
    int c = carry_s;
    __syncthreads();
    if (i < nb) bsum[i] = c + incl - v;
    if (t == 0) carry_s = c + tot;
    __syncthreads();
  }
}

// ---- scan pass 3: per-element exclusive scan + block offset -> row_ptr ----
__global__ void k_scan3(const int* __restrict__ x, const int* __restrict__ bsum,
                        int* __restrict__ rp, int n, int e) {
  __shared__ int sm[256];
  int t = threadIdx.x;
  int base = blockIdx.x * 1024;
  int v[4];
  int s = 0;
#pragma unroll
  for (int k = 0; k < 4; ++k) {
    int i = base + t * 4 + k;
    v[k] = (i < n) ? x[i] : 0;
    s += v[k];
  }
  sm[t] = s;
  __syncthreads();
  for (int o = 1; o < 256; o <<= 1) {
    int a = (t >= o) ? sm[t - o] : 0;
    __syncthreads();
    sm[t] += a;
    __syncthreads();
  }
  int excl = bsum[blockIdx.x] + sm[t] - s;
#pragma unroll
  for (int k = 0; k < 4; ++k) {
    int i = base + t * 4 + k;
    if (i < n) {
      rp[i] = excl;
      excl += v[k];
    }
  }
  if (blockIdx.x == 0 && t == 0) rp[n] = e;
}

// ---- bucket fill: CSR column (src) array ----
__global__ void k_fill(const int* __restrict__ src, const int* __restrict__ dst,
                       int* __restrict__ cur, int* __restrict__ sb, int e) {
  int i = blockIdx.x * 256 + threadIdx.x;
  if (i < e) {
    int pos = atomicAdd(&cur[dst[i]], 1);
    if ((unsigned)pos < (unsigned)e) sb[pos] = src[i];
  }
}

// ---- scale feature rows by per-node norm: P = feat * ns (dual-dtype input) ----
__global__ void k_scale(const void* __restrict__ x, const float* __restrict__ ns,
                        bf16* __restrict__ y, int nd, const int* __restrict__ mode) {
  int m = *mode;
  int i = blockIdx.x * 256 + threadIdx.x;
  if (i < nd) y[i] = __float2bfloat16(ldf(x, i, m) * ns[i >> 6]);
}

// ---- CSR gather-sum: one wave per node, lane = channel ----
__global__ void k_gather(const bf16* __restrict__ x, const int* __restrict__ rp,
                         const int* __restrict__ sb, bf16* __restrict__ y, int n) {
  int t = blockIdx.x * 256 + threadIdx.x;
  int lane = t & 63;
  int node = t >> 6;
  if (node >= n) return;
  int b = rp[node], e = rp[node + 1];
  float acc = 0.f;
  for (int o = b; o < e; ++o) {
    int s = sb[o];
    if ((unsigned)s < (unsigned)n) acc += __bfloat162float(x[s * DIM + lane]);
  }
  y[node * DIM + lane] = __float2bfloat16(acc);
}

// ---- 64x64 matmul: Y = post * relu(pre*(X@W) + b) ----
__global__ void __launch_bounds__(256) k_mm64(const bf16* __restrict__ X,
                                              const void* __restrict__ W,
                                              const void* __restrict__ b,
                                              const float* __restrict__ pre,
                                              const float* __restrict__ post,
                                              bf16* __restrict__ Y, int n, int relu,
                                              const int* __restrict__ mode) {
  int m = *mode;
  int t = threadIdx.x, lane = t & 63, wid = t >> 6;
  float w[64];
#pragma unroll
  for (int k = 0; k < 64; ++k) w[k] = ldf(W, k * 64 + lane, m);
  float bias = ldf(b, lane, m);
  int stride = gridDim.x * 4;
  for (int row = blockIdx.x * 4 + wid; row < n; row += stride) {
    float a = __bfloat162float(X[row * 64 + lane]);
    float acc = 0.f;
#pragma unroll
    for (int k = 0; k < 64; ++k) acc = fmaf(lane_bcast(a, k), w[k], acc);
    if (pre) acc *= pre[row];
    acc += bias;
    if (relu) acc = fmaxf(acc, 0.f);
    if (post) acc *= post[row];
    Y[row * 64 + lane] = __float2bfloat16(acc);
  }
}

// ---- per-column sum & sumsq (bf16 input) ----
__global__ void k_colstats(const bf16* __restrict__ X, float* __restrict__ s,
                           float* __restrict__ sq, int n) {
  int t = threadIdx.x, lane = t & 63, wid = t >> 6;
  float ps = 0.f, pq = 0.f;
  int stride = gridDim.x * 4;
  for (int row = blockIdx.x * 4 + wid; row < n; row += stride) {
    float v = __bfloat162float(X[row * 64 + lane]);
    ps += v;
    pq += v * v;
  }
  __shared__ float ssum[4][64], ssq[4][64];
  ssum[wid][lane] = ps;
  ssq[wid][lane] = pq;
  __syncthreads();
  if (t < 64) {
    float a = ssum[0][t] + ssum[1][t] + ssum[2][t] + ssum[3][t];
    float b2 = ssq[0][t] + ssq[1][t] + ssq[2][t] + ssq[3][t];
    atomicAdd(&s[t], a);
    atomicAdd(&sq[t], b2);
  }
}

// ---- standardize (ddof=1), write z to out (dual-dtype), acc 0.5*z into Dz ----
__global__ void k_z(const bf16* __restrict__ h, const float* __restrict__ s,
                    const float* __restrict__ sq, void* __restrict__ zout, long zoff,
                    bf16* __restrict__ zacc, int n, int init, const int* __restrict__ mode) {
  int m = *mode;
  int i = blockIdx.x * 256 + threadIdx.x;
  if (i >= n * DIM) return;
  int c = i & 63;
  float fn = (float)n;
  float mu = s[c] / fn;
  float var = (sq[c] - mu * mu * fn) / (fn - 1.0f);
  var = fmaxf(var, 1e-12f);  // never NaN; a stats bug shows as finite error
  float z = (__bfloat162float(h[i]) - mu) * rsqrtf(var);
  stf(zout, zoff + i, z, m);
  float prev = init ? 0.f : __bfloat162float(zacc[i]);
  zacc[i] = __float2bfloat16(prev + 0.5f * z);
}

// ---- BN (biased var) + relu + 64x40 matmul -> logits (dual-dtype out) ----
__global__ void __launch_bounds__(256) k_head(const bf16* __restrict__ Yv,
                                              const float* __restrict__ s,
                                              const float* __restrict__ sq,
                                              const void* __restrict__ gamma,
                                              const void* __restrict__ beta,
                                              const void* __restrict__ W2,
                                              const void* __restrict__ b2,
                                              void* __restrict__ out, long ooff, int n,
                                              const int* __restrict__ mode) {
  int m = *mode;
  int t = threadIdx.x, lane = t & 63, wid = t >> 6;
  float w[64];
#pragma unroll
  for (int k = 0; k < 64; ++k)
    w[k] = (lane < NCLS_OUT) ? ldf(W2, k * NCLS_OUT + lane, m) : 0.f;
  float bias = (lane < NCLS_OUT) ? ldf(b2, lane, m) : 0.f;
  float fn = (float)n;
  float mu = s[lane] / fn;
  float var = sq[lane] / fn - mu * mu;
  float rstd = rsqrtf(fmaxf(var, 0.f) + 1e-5f);
  float g = ldf(gamma, lane, m);
  float be = ldf(beta, lane, m);
  int stride = gridDim.x * 4;
  for (int row = blockIdx.x * 4 + wid; row < n; row += stride) {
    float yv = __bfloat162float(Yv[row * 64 + lane]);
    float yn = fmaxf((yv - mu) * rstd * g + be, 0.f);
    float acc = bias;
#pragma unroll
    for (int k = 0; k < 64; ++k) acc = fmaf(lane_bcast(yn, k), w[k], acc);
    if (lane < NCLS_OUT) stf(out, ooff + (long)row * NCLS_OUT + lane, acc, m);
  }
}

extern "C" void kernel_launch(void* const* d_in, const int* in_sizes, int n_in,
                              void* d_out, int out_size, void* d_ws, size_t ws_size,
                              hipStream_t stream) {
  const void* feat1 = d_in[0];
  const int* src1 = (const int*)d_in[1];
  const int* dst1 = (const int*)d_in[2];
  const void* feat2 = d_in[3];
  const int* src2 = (const int*)d_in[4];
  const int* dst2 = (const int*)d_in[5];
  const void* W1a = d_in[6];
  const void* b1a = d_in[7];
  const void* W1b = d_in[8];
  const void* b1b = d_in[9];
  const void* W2a = d_in[10];
  const void* b2a = d_in[11];
  const void* W2b = d_in[12];
  const void* b2b = d_in[13];
  const void* Wm1 = d_in[14];
  const void* bm1 = d_in[15];
  const void* gamma = d_in[16];
  const void* beta = d_in[17];
  const void* Wm2 = d_in[18];
  const void* bm2 = d_in[19];

  const int n = in_sizes[0] / DIM;
  const int e1 = in_sizes[1];
  const int e2 = in_sizes[4];
  const int emax = e1 > e2 ? e1 : e2;

  char* w = (char*)d_ws;
  size_t off = 0;
  auto alloc = [&](size_t bytes) -> void* {
    void* p = w + off;
    off += (bytes + 255) & ~(size_t)255;
    return p;
  };
  // ~49 MB total
  int* mode = (int*)alloc(256);
  int* deg = (int*)alloc((size_t)4 * n * 4);
  float* stats = (float*)alloc(512 * 4);
  float* norms = (float*)alloc((size_t)4 * n * 4);
  int* rp = (int*)alloc((size_t)(n + 8) * 4);
  int* cur = (int*)alloc((size_t)n * 4);
  int* bsum = (int*)alloc(1024 * 4);
  int* sb = (int*)alloc((size_t)emax * 4);
  bf16* P = (bf16*)alloc((size_t)n * DIM * 2);
  bf16* Q = (bf16*)alloc((size_t)n * DIM * 2);
  bf16* Dz = (bf16*)alloc((size_t)n * DIM * 2);

  const float* ns1 = norms;
  const float* nd1 = norms + n;
  const float* ns2 = norms + 2 * n;
  const float* nd2 = norms + 3 * n;

  int gE1 = (e1 + 255) / 256, gE2 = (e2 + 255) / 256;
  int gND = (n * DIM + 255) / 256;
  int g4N = (4 * n + 255) / 256;
  int nb = (n + 1023) / 1024;

  hipMemsetAsync(deg, 0, (size_t)4 * n * 4, stream);
  hipMemsetAsync(stats, 0, 512 * 4, stream);

  k_detect<<<1, 256, 0, stream>>>((const unsigned int*)feat1, 65536, mode);

  k_deg<<<gE1, 256, 0, stream>>>(src1, dst1, deg, deg + n, e1);
  k_deg<<<gE2, 256, 0, stream>>>(src2, dst2, deg + 2 * n, deg + 3 * n, e2);
  k_norm<<<g4N, 256, 0, stream>>>(deg, norms, 4 * n);

  // ---- CSR graph 1 (by dst), then GCN 1 ----
  k_scan1<<<nb, 256, 0, stream>>>(deg + n, bsum, n);
  k_scan2<<<1, 256, 0, stream>>>(bsum, nb);
  k_scan3<<<nb, 256, 0, stream>>>(deg + n, bsum, rp, n, e1);
  hipMemcpyAsync(cur, rp, (size_t)n * 4, hipMemcpyDeviceToDevice, stream);
  k_fill<<<gE1, 256, 0, stream>>>(src1, dst1, cur, sb, e1);

  k_scale<<<gND, 256, 0, stream>>>(feat1, ns1, P, n * DIM, mode);
  k_gather<<<gND, 256, 0, stream>>>(P, rp, sb, Q, n);
  k_mm64<<<512, 256, 0, stream>>>(Q, W1a, b1a, nd1, ns1, P, n, 1, mode);
  k_gather<<<gND, 256, 0, stream>>>(P, rp, sb, Q, n);
  k_mm64<<<512, 256, 0, stream>>>(Q, W1b, b1b, nd1, (const float*)nullptr, P, n, 0, mode);
  k_colstats<<<512, 256, 0, stream>>>(P, stats + 0, stats + 64, n);
  k_z<<<gND, 256, 0, stream>>>(P, stats + 0, stats + 64, d_out, 0L, Dz, n, 1, mode);

  // ---- CSR graph 2 (reuses rp/cur/sb), then GCN 2 ----
  k_scan1<<<nb, 256, 0, stream>>>(deg + 3 * n, bsum, n);
  k_scan2<<<1, 256, 0, stream>>>(bsum, nb);
  k_scan3<<<nb, 256, 0, stream>>>(deg + 3 * n, bsum, rp, n, e2);
  hipMemcpyAsync(cur, rp, (size_t)n * 4, hipMemcpyDeviceToDevice, stream);
  k_fill<<<gE2, 256, 0, stream>>>(src2, dst2, cur, sb, e2);

  k_scale<<<gND, 256, 0, stream>>>(feat2, ns2, P, n * DIM, mode);
  k_gather<<<gND, 256, 0, stream>>>(P, rp, sb, Q, n);
  k_mm64<<<512, 256, 0, stream>>>(Q, W2a, b2a, nd2, ns2, P, n, 1, mode);
  k_gather<<<gND, 256, 0, stream>>>(P, rp, sb, Q, n);
  k_mm64<<<512, 256, 0, stream>>>(Q, W2b, b2b, nd2, (const float*)nullptr, P, n, 0, mode);
  k_colstats<<<512, 256, 0, stream>>>(P, stats + 128, stats + 192, n);
  k_z<<<gND, 256, 0, stream>>>(P, stats + 128, stats + 192, d_out, (long)n * DIM, Dz, n, 0, mode);

  // ---- head: y = Dz@Wm1+bm1 ; BN ; relu ; @Wm2+bm2 ----
  k_mm64<<<512, 256, 0, stream>>>(Dz, Wm1, bm1, (const float*)nullptr, (const float*)nullptr,
                                  P, n, 0, mode);
  k_colstats<<<512, 256, 0, stream>>>(P, stats + 256, stats + 320, n);
  k_head<<<512, 256, 0, stream>>>(P, stats + 256, stats + 320, gamma, beta, Wm2, bm2,
                                  d_out, (long)2 * n * DIM, n, mode);
}

// Round 4
// 1376.370 us; speedup vs baseline: 1.2519x; 1.2519x over previous
//
#include <hip/hip_runtime.h>
#include <hip/hip_bf16.h>

#define DIM 64
#define NCLS_OUT 40

typedef __hip_bfloat16 bf16;

__device__ __forceinline__ float lane_bcast(float v, int l) {
  return __int_as_float(__builtin_amdgcn_readlane(__float_as_int(v), l));
}
__device__ __forceinline__ unsigned short f2bf_bits(float f) {
  bf16 h = __float2bfloat16(f);
  return *reinterpret_cast<unsigned short*>(&h);
}

// mode: 1 = float inputs/outputs stored as f32, 0 = stored as bf16
__device__ __forceinline__ float ldf(const void* p, long i, int m) {
  return m ? ((const float*)p)[i] : __bfloat162float(((const bf16*)p)[i]);
}
__device__ __forceinline__ void stf(void* p, long i, float v, int m) {
  if (m) ((float*)p)[i] = v;
  else ((bf16*)p)[i] = __float2bfloat16(v);
}

// ---- dtype detector ----
__global__ void k_detect(const unsigned int* __restrict__ wds, int nw, int* __restrict__ mode) {
  __shared__ int cnt_s;
  if (threadIdx.x == 0) cnt_s = 0;
  __syncthreads();
  int c = 0;
  for (int i = threadIdx.x; i < nw; i += 1024) {
    unsigned h = wds[i] & 0xFFFFu;
    unsigned e = (h >> 7) & 0xFFu;
    if (e == 0xFFu || (e != 0u && e < 0x60u)) c++;
  }
  atomicAdd(&cnt_s, c);
  __syncthreads();
  if (threadIdx.x == 0) *mode = (cnt_s > nw / 16) ? 1 : 0;
}

// ---- degree count ----
__global__ void k_deg(const int* __restrict__ src, const int* __restrict__ dst,
                      int* __restrict__ dout, int* __restrict__ din, int e) {
  int i = blockIdx.x * 256 + threadIdx.x;
  if (i < e) {
    atomicAdd(&dout[src[i]], 1);
    atomicAdd(&din[dst[i]], 1);
  }
}

// ---- norms = rsqrt(max(deg,1)) ----
__global__ void k_norm(const int* __restrict__ deg, float* __restrict__ nrm, int n4) {
  int i = blockIdx.x * 256 + threadIdx.x;
  if (i < n4) {
    int d = deg[i];
    if (d < 1) d = 1;
    nrm[i] = rsqrtf((float)d);
  }
}

// ---- scan pass 1 ----
__global__ void k_scan1(const int* __restrict__ x, int* __restrict__ bsum, int n) {
  __shared__ int sm[256];
  int t = threadIdx.x;
  int base = blockIdx.x * 1024 + t * 4;
  int s = 0;
#pragma unroll
  for (int k = 0; k < 4; ++k) {
    int i = base + k;
    if (i < n) s += x[i];
  }
  sm[t] = s;
  __syncthreads();
  for (int o = 128; o > 0; o >>= 1) {
    if (t < o) sm[t] += sm[t + o];
    __syncthreads();
  }
  if (t == 0) bsum[blockIdx.x] = sm[0];
}

// ---- scan pass 2 ----
__global__ void k_scan2(int* __restrict__ bsum, int nb) {
  __shared__ int sm[256];
  __shared__ int carry_s;
  int t = threadIdx.x;
  if (t == 0) carry_s = 0;
  __syncthreads();
  for (int base = 0; base < nb; base += 256) {
    int i = base + t;
    int v = (i < nb) ? bsum[i] : 0;
    sm[t] = v;
    __syncthreads();
    for (int o = 1; o < 256; o <<= 1) {
      int a = (t >= o) ? sm[t - o] : 0;
      __syncthreads();
      sm[t] += a;
      __syncthreads();
    }
    int incl = sm[t];
    int tot = sm[255];
    int c = carry_s;
    __syncthreads();
    if (i < nb) bsum[i] = c + incl - v;
    if (t == 0) carry_s = c + tot;
    __syncthreads();
  }
}

// ---- scan pass 3 ----
__global__ void k_scan3(const int* __restrict__ x, const int* __restrict__ bsum,
                        int* __restrict__ rp, int n, int e) {
  __shared__ int sm[256];
  int t = threadIdx.x;
  int base = blockIdx.x * 1024;
  int v[4];
  int s = 0;
#pragma unroll
  for (int k = 0; k < 4; ++k) {
    int i = base + t * 4 + k;
    v[k] = (i < n) ? x[i] : 0;
    s += v[k];
  }
  sm[t] = s;
  __syncthreads();
  for (int o = 1; o < 256; o <<= 1) {
    int a = (t >= o) ? sm[t - o] : 0;
    __syncthreads();
    sm[t] += a;
    __syncthreads();
  }
  int excl = bsum[blockIdx.x] + sm[t] - s;
#pragma unroll
  for (int k = 0; k < 4; ++k) {
    int i = base + t * 4 + k;
    if (i < n) {
      rp[i] = excl;
      excl += v[k];
    }
  }
  if (blockIdx.x == 0 && t == 0) rp[n] = e;
}

// ---- bucket fill ----
__global__ void k_fill(const int* __restrict__ src, const int* __restrict__ dst,
                       int* __restrict__ cur, int* __restrict__ sb, int e) {
  int i = blockIdx.x * 256 + threadIdx.x;
  if (i < e) {
    int pos = atomicAdd(&cur[dst[i]], 1);
    if ((unsigned)pos < (unsigned)e) sb[pos] = src[i];
  }
}

// ---- P = feat * ns ----
__global__ void k_scale(const void* __restrict__ x, const float* __restrict__ ns,
                        bf16* __restrict__ y, int nd, const int* __restrict__ mode) {
  int m = *mode;
  int i = blockIdx.x * 256 + threadIdx.x;
  if (i < nd) y[i] = __float2bfloat16(ldf(x, i, m) * ns[i >> 6]);
}

// ---- fused CSR gather + 64x64 matmul ----
// Y[node] = post * relu( (pre * sum_{s in N(node)} X[s]) @ W + b )
__global__ void __launch_bounds__(256) k_gmm(const bf16* __restrict__ X,
                                             const int* __restrict__ rp,
                                             const int* __restrict__ sb,
                                             const void* __restrict__ W,
                                             const void* __restrict__ b,
                                             const float* __restrict__ pre,
                                             const float* __restrict__ post,
                                             bf16* __restrict__ Y, int n, int relu,
                                             const int* __restrict__ mode) {
  int m = *mode;
  int t = threadIdx.x, lane = t & 63, wid = t >> 6;
  // W packed as bf16x2 in 32 VGPRs: lane holds output column `lane`
  unsigned wp[32];
#pragma unroll
  for (int i = 0; i < 32; ++i) {
    unsigned lb = f2bf_bits(ldf(W, (2 * i) * 64 + lane, m));
    unsigned hb = f2bf_bits(ldf(W, (2 * i + 1) * 64 + lane, m));
    wp[i] = lb | (hb << 16);
  }
  float bias = ldf(b, lane, m);
  int gwid = blockIdx.x * 4 + wid, nw = gridDim.x * 4;
  for (int node = gwid; node < n; node += nw) {
    int b0 = rp[node], e0 = rp[node + 1];
    float a0 = 0.f, a1 = 0.f, a2 = 0.f, a3 = 0.f;
    for (int base = b0; base < e0; base += 64) {
      int cnt = e0 - base;
      if (cnt > 64) cnt = 64;
      int eidx = (lane < cnt) ? sb[base + lane] : 0;
      int j = 0;
      for (; j + 4 <= cnt; j += 4) {
        int s0 = __builtin_amdgcn_readlane(eidx, j);
        int s1 = __builtin_amdgcn_readlane(eidx, j + 1);
        int s2 = __builtin_amdgcn_readlane(eidx, j + 2);
        int s3 = __builtin_amdgcn_readlane(eidx, j + 3);
        float v0 = __bfloat162float(X[s0 * DIM + lane]);
        float v1 = __bfloat162float(X[s1 * DIM + lane]);
        float v2 = __bfloat162float(X[s2 * DIM + lane]);
        float v3 = __bfloat162float(X[s3 * DIM + lane]);
        a0 += v0; a1 += v1; a2 += v2; a3 += v3;
      }
      for (; j < cnt; ++j) {
        int s0 = __builtin_amdgcn_readlane(eidx, j);
        a0 += __bfloat162float(X[s0 * DIM + lane]);
      }
    }
    float acc = (a0 + a1) + (a2 + a3);
    if (pre) acc *= pre[node];
    float r = 0.f;
#pragma unroll
    for (int i = 0; i < 32; ++i) {
      r = fmaf(lane_bcast(acc, 2 * i), __uint_as_float(wp[i] << 16), r);
      r = fmaf(lane_bcast(acc, 2 * i + 1), __uint_as_float(wp[i] & 0xFFFF0000u), r);
    }
    r += bias;
    if (relu) r = fmaxf(r, 0.f);
    if (post) r *= post[node];
    Y[(long)node * DIM + lane] = __float2bfloat16(r);
  }
}

// ---- plain 64x64 matmul (head) ----
__global__ void __launch_bounds__(256) k_mm64(const bf16* __restrict__ X,
                                              const void* __restrict__ W,
                                              const void* __restrict__ b,
                                              bf16* __restrict__ Y, int n,
                                              const int* __restrict__ mode) {
  int m = *mode;
  int t = threadIdx.x, lane = t & 63, wid = t >> 6;
  float w[64];
#pragma unroll
  for (int k = 0; k < 64; ++k) w[k] = ldf(W, k * 64 + lane, m);
  float bias = ldf(b, lane, m);
  int stride = gridDim.x * 4;
  for (int row = blockIdx.x * 4 + wid; row < n; row += stride) {
    float a = __bfloat162float(X[row * 64 + lane]);
    float acc = 0.f;
#pragma unroll
    for (int k = 0; k < 64; ++k) acc = fmaf(lane_bcast(a, k), w[k], acc);
    acc += bias;
    Y[row * 64 + lane] = __float2bfloat16(acc);
  }
}

// ---- per-column sum & sumsq ----
__global__ void k_colstats(const bf16* __restrict__ X, float* __restrict__ s,
                           float* __restrict__ sq, int n) {
  int t = threadIdx.x, lane = t & 63, wid = t >> 6;
  float ps = 0.f, pq = 0.f;
  int stride = gridDim.x * 4;
  for (int row = blockIdx.x * 4 + wid; row < n; row += stride) {
    float v = __bfloat162float(X[row * 64 + lane]);
    ps += v;
    pq += v * v;
  }
  __shared__ float ssum[4][64], ssq[4][64];
  ssum[wid][lane] = ps;
  ssq[wid][lane] = pq;
  __syncthreads();
  if (t < 64) {
    float a = ssum[0][t] + ssum[1][t] + ssum[2][t] + ssum[3][t];
    float b2 = ssq[0][t] + ssq[1][t] + ssq[2][t] + ssq[3][t];
    atomicAdd(&s[t], a);
    atomicAdd(&sq[t], b2);
  }
}

// ---- standardize (ddof=1), write z, acc 0.5*z into Dz ----
__global__ void k_z(const bf16* __restrict__ h, const float* __restrict__ s,
                    const float* __restrict__ sq, void* __restrict__ zout, long zoff,
                    bf16* __restrict__ zacc, int n, int init, const int* __restrict__ mode) {
  int m = *mode;
  int i = blockIdx.x * 256 + threadIdx.x;
  if (i >= n * DIM) return;
  int c = i & 63;
  float fn = (float)n;
  float mu = s[c] / fn;
  float var = (sq[c] - mu * mu * fn) / (fn - 1.0f);
  var = fmaxf(var, 1e-12f);
  float z = (__bfloat162float(h[i]) - mu) * rsqrtf(var);
  stf(zout, zoff + i, z, m);
  float prev = init ? 0.f : __bfloat162float(zacc[i]);
  zacc[i] = __float2bfloat16(prev + 0.5f * z);
}

// ---- BN + relu + 64x40 matmul -> logits ----
__global__ void __launch_bounds__(256) k_head(const bf16* __restrict__ Yv,
                                              const float* __restrict__ s,
                                              const float* __restrict__ sq,
                                              const void* __restrict__ gamma,
                                              const void* __restrict__ beta,
                                              const void* __restrict__ W2,
                                              const void* __restrict__ b2,
                                              void* __restrict__ out, long ooff, int n,
                                              const int* __restrict__ mode) {
  int m = *mode;
  int t = threadIdx.x, lane = t & 63, wid = t >> 6;
  float w[64];
#pragma unroll
  for (int k = 0; k < 64; ++k)
    w[k] = (lane < NCLS_OUT) ? ldf(W2, k * NCLS_OUT + lane, m) : 0.f;
  float bias = (lane < NCLS_OUT) ? ldf(b2, lane, m) : 0.f;
  float fn = (float)n;
  float mu = s[lane] / fn;
  float var = sq[lane] / fn - mu * mu;
  float rstd = rsqrtf(fmaxf(var, 0.f) + 1e-5f);
  float g = ldf(gamma, lane, m);
  float be = ldf(beta, lane, m);
  int stride = gridDim.x * 4;
  for (int row = blockIdx.x * 4 + wid; row < n; row += stride) {
    float yv = __bfloat162float(Yv[row * 64 + lane]);
    float yn = fmaxf((yv - mu) * rstd * g + be, 0.f);
    float acc = bias;
#pragma unroll
    for (int k = 0; k < 64; ++k) acc = fmaf(lane_bcast(yn, k), w[k], acc);
    if (lane < NCLS_OUT) stf(out, ooff + (long)row * NCLS_OUT + lane, acc, m);
  }
}

extern "C" void kernel_launch(void* const* d_in, const int* in_sizes, int n_in,
                              void* d_out, int out_size, void* d_ws, size_t ws_size,
                              hipStream_t stream) {
  const void* feat1 = d_in[0];
  const int* src1 = (const int*)d_in[1];
  const int* dst1 = (const int*)d_in[2];
  const void* feat2 = d_in[3];
  const int* src2 = (const int*)d_in[4];
  const int* dst2 = (const int*)d_in[5];
  const void* W1a = d_in[6];
  const void* b1a = d_in[7];
  const void* W1b = d_in[8];
  const void* b1b = d_in[9];
  const void* W2a = d_in[10];
  const void* b2a = d_in[11];
  const void* W2b = d_in[12];
  const void* b2b = d_in[13];
  const void* Wm1 = d_in[14];
  const void* bm1 = d_in[15];
  const void* gamma = d_in[16];
  const void* beta = d_in[17];
  const void* Wm2 = d_in[18];
  const void* bm2 = d_in[19];

  const int n = in_sizes[0] / DIM;
  const int e1 = in_sizes[1];
  const int e2 = in_sizes[4];
  const int emax = e1 > e2 ? e1 : e2;

  char* w = (char*)d_ws;
  size_t off = 0;
  auto alloc = [&](size_t bytes) -> void* {
    void* p = w + off;
    off += (bytes + 255) & ~(size_t)255;
    return p;
  };
  int* mode = (int*)alloc(256);
  int* deg = (int*)alloc((size_t)4 * n * 4);
  float* stats = (float*)alloc(512 * 4);
  float* norms = (float*)alloc((size_t)4 * n * 4);
  int* rp = (int*)alloc((size_t)(n + 8) * 4);
  int* cur = (int*)alloc((size_t)n * 4);
  int* bsum = (int*)alloc(1024 * 4);
  int* sb = (int*)alloc((size_t)emax * 4);
  bf16* P = (bf16*)alloc((size_t)n * DIM * 2);
  bf16* Q = (bf16*)alloc((size_t)n * DIM * 2);
  bf16* Dz = (bf16*)alloc((size_t)n * DIM * 2);

  const float* ns1 = norms;
  const float* nd1 = norms + n;
  const float* ns2 = norms + 2 * n;
  const float* nd2 = norms + 3 * n;

  int gE1 = (e1 + 255) / 256, gE2 = (e2 + 255) / 256;
  int gND = (n * DIM + 255) / 256;
  int g4N = (4 * n + 255) / 256;
  int nb = (n + 1023) / 1024;
  const int gGMM = 2048;  // 8192 waves -> 8/SIMD at <=64 VGPR

  hipMemsetAsync(deg, 0, (size_t)4 * n * 4, stream);
  hipMemsetAsync(stats, 0, 512 * 4, stream);

  k_detect<<<1, 1024, 0, stream>>>((const unsigned int*)feat1, 8192, mode);

  k_deg<<<gE1, 256, 0, stream>>>(src1, dst1, deg, deg + n, e1);
  k_deg<<<gE2, 256, 0, stream>>>(src2, dst2, deg + 2 * n, deg + 3 * n, e2);
  k_norm<<<g4N, 256, 0, stream>>>(deg, norms, 4 * n);

  // ---- CSR graph 1 (by dst), GCN 1 ----
  k_scan1<<<nb, 256, 0, stream>>>(deg + n, bsum, n);
  k_scan2<<<1, 256, 0, stream>>>(bsum, nb);
  k_scan3<<<nb, 256, 0, stream>>>(deg + n, bsum, rp, n, e1);
  hipMemcpyAsync(cur, rp, (size_t)n * 4, hipMemcpyDeviceToDevice, stream);
  k_fill<<<gE1, 256, 0, stream>>>(src1, dst1, cur, sb, e1);

  k_scale<<<gND, 256, 0, stream>>>(feat1, ns1, P, n * DIM, mode);
  k_gmm<<<gGMM, 256, 0, stream>>>(P, rp, sb, W1a, b1a, nd1, ns1, Q, n, 1, mode);
  k_gmm<<<gGMM, 256, 0, stream>>>(Q, rp, sb, W1b, b1b, nd1, (const float*)nullptr, P, n, 0, mode);
  k_colstats<<<512, 256, 0, stream>>>(P, stats + 0, stats + 64, n);
  k_z<<<gND, 256, 0, stream>>>(P, stats + 0, stats + 64, d_out, 0L, Dz, n, 1, mode);

  // ---- CSR graph 2 (reuses rp/cur/sb), GCN 2 ----
  k_scan1<<<nb, 256, 0, stream>>>(deg + 3 * n, bsum, n);
  k_scan2<<<1, 256, 0, stream>>>(bsum, nb);
  k_scan3<<<nb, 256, 0, stream>>>(deg + 3 * n, bsum, rp, n, e2);
  hipMemcpyAsync(cur, rp, (size_t)n * 4, hipMemcpyDeviceToDevice, stream);
  k_fill<<<gE2, 256, 0, stream>>>(src2, dst2, cur, sb, e2);

  k_scale<<<gND, 256, 0, stream>>>(feat2, ns2, P, n * DIM, mode);
  k_gmm<<<gGMM, 256, 0, stream>>>(P, rp, sb, W2a, b2a, nd2, ns2, Q, n, 1, mode);
  k_gmm<<<gGMM, 256, 0, stream>>>(Q, rp, sb, W2b, b2b, nd2, (const float*)nullptr, P, n, 0, mode);
  k_colstats<<<512, 256, 0, stream>>>(P, stats + 128, stats + 192, n);
  k_z<<<gND, 256, 0, stream>>>(P, stats + 128, stats + 192, d_out, (long)n * DIM, Dz, n, 0, mode);

  // ---- head ----
  k_mm64<<<512, 256, 0, stream>>>(Dz, Wm1, bm1, P, n, mode);
  k_colstats<<<512, 256, 0, stream>>>(P, stats + 256, stats + 320, n);
  k_head<<<512, 256, 0, stream>>>(P, stats + 256, stats + 320, gamma, beta, Wm2, bm2,
                                  d_out, (long)2 * n * DIM, n, mode);
}